// Round 1
// baseline (1523.998 us; speedup 1.0000x reference)
//
#include <hip/hip_runtime.h>
#include <hip/hip_bf16.h>
#include <stdint.h>

#define DEV static __device__ __forceinline__

using f32x4  = __attribute__((ext_vector_type(4))) float;
using bf16x8 = __attribute__((ext_vector_type(8))) __bf16;

constexpr int SEQ = 2048;
constexpr int NHEAD = 16;

DEV unsigned short f2bf(float f) {
  union { float f; unsigned u; } c; c.f = f;
  unsigned u = c.u;
  u += 0x7fffu + ((u >> 16) & 1u);   // RNE
  return (unsigned short)(u >> 16);
}
DEV float bf2f(unsigned short h) {
  union { unsigned u; float f; } c; c.u = ((unsigned)h) << 16;
  return c.f;
}

DEV float wred_max(float v) {
  #pragma unroll
  for (int m = 32; m > 0; m >>= 1) v = fmaxf(v, __shfl_xor(v, m, 64));
  return v;
}
DEV float wred_sum(float v) {
  #pragma unroll
  for (int m = 32; m > 0; m >>= 1) v += __shfl_xor(v, m, 64);
  return v;
}

// ---------------- weight transpose + fp32->bf16 convert ----------------
// in: [H][K][Nh] fp32, out: [H*Nh][K] bf16  (out[n][k] = in[h][k][nh], n = h*Nh+nh)
__global__ __launch_bounds__(256) void convw_kernel(
    const float* __restrict__ in, unsigned short* __restrict__ out,
    int K, int Nh)
{
  const int h = blockIdx.z;
  const float* inh = in + (size_t)h * K * Nh;
  unsigned short* outh = out + (size_t)h * Nh * K;
  const int n0 = blockIdx.x * 32, k0 = blockIdx.y * 32;
  __shared__ float t[32][33];
  const int tx = threadIdx.x & 31, ty = threadIdx.x >> 5;
  #pragma unroll
  for (int r = 0; r < 32; r += 8)
    t[ty + r][tx] = inh[(size_t)(k0 + ty + r) * Nh + (n0 + tx)];
  __syncthreads();
  #pragma unroll
  for (int r = 0; r < 32; r += 8)
    outh[(size_t)(n0 + ty + r) * K + (k0 + tx)] = f2bf(t[tx][ty + r]);
}

// ---------------- LayerNorm (fp32 in) -> bf16 out ----------------
__global__ __launch_bounds__(256) void ln_kernel(
    const float* __restrict__ x, const float* __restrict__ w,
    const float* __restrict__ b, unsigned short* __restrict__ out)
{
  const int row = blockIdx.x;
  const int tid = threadIdx.x;
  const float4 v = ((const float4*)(x + (size_t)row * 1024))[tid];
  float s  = v.x + v.y + v.z + v.w;
  float s2 = v.x*v.x + v.y*v.y + v.z*v.z + v.w*v.w;
  s = wred_sum(s); s2 = wred_sum(s2);
  __shared__ float rs[4], rs2[4];
  const int wave = tid >> 6, lane = tid & 63;
  if (lane == 0) { rs[wave] = s; rs2[wave] = s2; }
  __syncthreads();
  const float S  = rs[0] + rs[1] + rs[2] + rs[3];
  const float S2 = rs2[0] + rs2[1] + rs2[2] + rs2[3];
  const float mean = S * (1.f / 1024.f);
  const float var  = S2 * (1.f / 1024.f) - mean * mean;
  const float inv  = rsqrtf(var + 1e-5f);
  const float4 wv = ((const float4*)w)[tid];
  const float4 bv = ((const float4*)b)[tid];
  ushort4 o;
  o.x = f2bf((v.x - mean) * inv * wv.x + bv.x);
  o.y = f2bf((v.y - mean) * inv * wv.y + bv.y);
  o.z = f2bf((v.z - mean) * inv * wv.z + bv.z);
  o.w = f2bf((v.w - mean) * inv * wv.w + bv.w);
  ((ushort4*)(out + (size_t)row * 1024))[tid] = o;
}

// ---------------- GEMM: C[M,N] = A[M,K] * BT[N,K]^T  (bf16 in, fp32 acc) ----
// EPI 0: store bf16
// EPI 1: store fp32 = acc + bias[col] + res[row*N+col]
// EPI 2: store bf16 = relu(acc + bias[col])
#define BM 128
#define BN 128
#define BK 32
template<int EPI>
__global__ __launch_bounds__(256) void gemm_bt(
    const unsigned short* __restrict__ A, const unsigned short* __restrict__ BT,
    void* __restrict__ Cout, const float* __restrict__ bias,
    const float* __restrict__ res, int M, int N, int K)
{
  __shared__ unsigned short sA[BM * BK];
  __shared__ unsigned short sB[BN * BK];
  const int tid = threadIdx.x;
  const int wave = tid >> 6, lane = tid & 63;
  const int wr = wave >> 1, wc = wave & 1;     // 2x2 wave grid -> 64x64 each
  const int m0 = blockIdx.y * BM, n0 = blockIdx.x * BN;
  const int lr = lane & 15, lg = lane >> 4;

  const f32x4 zero = {0.f, 0.f, 0.f, 0.f};
  f32x4 acc[4][4];
  #pragma unroll
  for (int i = 0; i < 4; ++i)
    #pragma unroll
    for (int j = 0; j < 4; ++j) acc[i][j] = zero;

  for (int k0 = 0; k0 < K; k0 += BK) {
    // stage 128x32 A-tile and 128x32 B-tile (each 8KB)
    #pragma unroll
    for (int r = 0; r < 2; ++r) {
      const int c = tid + 256 * r;
      const int row = c >> 2, off = (c & 3) * 8;
      const int4 va = *(const int4*)(A + (size_t)(m0 + row) * K + k0 + off);
      *(int4*)(sA + row * BK + off) = va;
      const int4 vb = *(const int4*)(BT + (size_t)(n0 + row) * K + k0 + off);
      *(int4*)(sB + row * BK + off) = vb;
    }
    __syncthreads();
    bf16x8 af[4], bfr[4];
    #pragma unroll
    for (int i = 0; i < 4; ++i) {
      af[i]  = *(const bf16x8*)(sA + (wr * 64 + i * 16 + lr) * BK + lg * 8);
      bfr[i] = *(const bf16x8*)(sB + (wc * 64 + i * 16 + lr) * BK + lg * 8);
    }
    #pragma unroll
    for (int i = 0; i < 4; ++i)
      #pragma unroll
      for (int j = 0; j < 4; ++j)
        acc[i][j] = __builtin_amdgcn_mfma_f32_16x16x32_bf16(af[i], bfr[j], acc[i][j], 0, 0, 0);
    __syncthreads();
  }
  // epilogue: C/D layout col=lane&15, row=(lane>>4)*4+reg  [verified m89/m91]
  #pragma unroll
  for (int i = 0; i < 4; ++i) {
    #pragma unroll
    for (int j = 0; j < 4; ++j) {
      #pragma unroll
      for (int r = 0; r < 4; ++r) {
        const int row = m0 + wr * 64 + i * 16 + lg * 4 + r;
        const int col = n0 + wc * 64 + j * 16 + lr;
        const float v = acc[i][j][r];
        if (EPI == 0) {
          ((unsigned short*)Cout)[(size_t)row * N + col] = f2bf(v);
        } else if (EPI == 1) {
          ((float*)Cout)[(size_t)row * N + col] = v + bias[col] + res[(size_t)row * N + col];
        } else {
          float t = v + bias[col];
          t = t > 0.f ? t : 0.f;
          ((unsigned short*)Cout)[(size_t)row * N + col] = f2bf(t);
        }
      }
    }
  }
}

// ---------------- causal attention (flash-style, one query row per wave) ----
// qkv: [B*S][3072] bf16 (q | k | v, each head-major h*64+dh), o: [B*S][1024] bf16
__global__ __launch_bounds__(256) void attn_kernel(
    const unsigned short* __restrict__ qkv, unsigned short* __restrict__ o)
{
  const int blk = blockIdx.x;
  const int bh = blk >> 9;                 // 512 blocks per (b,h): S/4
  const int i0 = (blk & 511) * 4;
  const int b = bh >> 4, h = bh & 15;
  const int wave = threadIdx.x >> 6, lane = threadIdx.x & 63;
  const int i = i0 + wave;                 // this wave's query row

  __shared__ float Kt[64][65];             // padded: bank = (j+d)%32, conflict-free
  __shared__ float Vt[64][64];
  __shared__ float p_lds[4][64];
  __shared__ float q_lds[4][64];

  const size_t qrow = ((size_t)(b * SEQ + i)) * 3072 + h * 64;
  q_lds[wave][lane] = bf2f(qkv[qrow + lane]);

  float m_run = -1e30f, l_run = 0.f, oacc = 0.f;
  const int i_max = i0 + 3;
  const int ntiles = i_max / 64 + 1;

  const int tid = threadIdx.x;
  const int sj = tid >> 2;                 // staging: key row
  const int sd = (tid & 3) * 16;           // staging: dim start

  for (int t = 0; t < ntiles; ++t) {
    const int j0 = t * 64;
    __syncthreads();
    {
      const int gj = j0 + sj;
      if (gj < SEQ) {
        const size_t base = ((size_t)(b * SEQ + gj)) * 3072 + h * 64;
        #pragma unroll
        for (int half = 0; half < 2; ++half) {
          int4 rk = *(const int4*)(qkv + base + 1024 + sd + half * 8);
          const unsigned short* uk = (const unsigned short*)&rk;
          #pragma unroll
          for (int e = 0; e < 8; ++e) Kt[sj][sd + half * 8 + e] = bf2f(uk[e]);
          int4 rv = *(const int4*)(qkv + base + 2048 + sd + half * 8);
          const unsigned short* uv = (const unsigned short*)&rv;
          #pragma unroll
          for (int e = 0; e < 8; ++e) Vt[sj][sd + half * 8 + e] = bf2f(uv[e]);
        }
      } else {
        #pragma unroll
        for (int e = 0; e < 16; ++e) { Kt[sj][sd + e] = 0.f; Vt[sj][sd + e] = 0.f; }
      }
    }
    __syncthreads();

    // scores: lane = key j0+lane
    float s = 0.f;
    #pragma unroll 8
    for (int d = 0; d < 64; ++d) s += q_lds[wave][d] * Kt[lane][d];
    const bool valid = (j0 + lane <= i);
    const float sv = valid ? s * 0.125f : -1e30f;
    const float tmax = wred_max(sv);
    const float m_new = fmaxf(m_run, tmax);
    const float scale = __expf(m_run - m_new);
    const float p = valid ? __expf(sv - m_new) : 0.f;
    const float tsum = wred_sum(p);
    l_run = l_run * scale + tsum;
    oacc *= scale;
    m_run = m_new;
    p_lds[wave][lane] = p;

    // PV: lane = dim
    #pragma unroll 8
    for (int jj = 0; jj < 64; ++jj) oacc += p_lds[wave][jj] * Vt[jj][lane];
  }
  o[((size_t)(b * SEQ + i)) * 1024 + h * 64 + lane] = f2bf(oacc / l_run);
}

extern "C" void kernel_launch(void* const* d_in, const int* in_sizes, int n_in,
                              void* d_out, int out_size, void* d_ws, size_t ws_size,
                              hipStream_t stream) {
  const float* x    = (const float*)d_in[0];
  const float* Wq   = (const float*)d_in[2];
  const float* Wk   = (const float*)d_in[3];
  const float* Wv   = (const float*)d_in[4];
  const float* Wo   = (const float*)d_in[5];
  const float* bo   = (const float*)d_in[6];
  const float* W1   = (const float*)d_in[7];
  const float* b1   = (const float*)d_in[8];
  const float* W2   = (const float*)d_in[9];
  const float* b2   = (const float*)d_in[10];
  const float* ln1w = (const float*)d_in[11];
  const float* ln1b = (const float*)d_in[12];
  const float* ln2w = (const float*)d_in[13];
  const float* ln2b = (const float*)d_in[14];

  // workspace layout (80 MB total)
  char* ws = (char*)d_ws;
  unsigned short* WqkvT = (unsigned short*)(ws);             // [3072][1024] bf16
  unsigned short* WoT   = (unsigned short*)(ws + 6291456);   // [1024][1024]
  unsigned short* W1T   = (unsigned short*)(ws + 8388608);   // [4096][1024]
  unsigned short* W2T   = (unsigned short*)(ws + 16777216);  // [1024][4096]
  unsigned short* xn    = (unsigned short*)(ws + 25165824);  // [4096][1024] (xn1, reused as xn2)
  float*          x1    = (float*)        (ws + 33554432);   // [4096][1024] fp32
  unsigned short* qkv   = (unsigned short*)(ws + 50331648);  // [4096][3072]
  unsigned short* oc    = (unsigned short*)(ws + 75497472);  // [4096][1024]
  unsigned short* hbuf  = qkv;                               // [4096][4096] aliases qkv+oc (dead after Wo proj)

  // 1. weights -> bf16, transposed to [N][K]
  convw_kernel<<<dim3(2, 32, 16),  256, 0, stream>>>(Wq, WqkvT,               1024, 64);
  convw_kernel<<<dim3(2, 32, 16),  256, 0, stream>>>(Wk, WqkvT + 1024 * 1024, 1024, 64);
  convw_kernel<<<dim3(2, 32, 16),  256, 0, stream>>>(Wv, WqkvT + 2048 * 1024, 1024, 64);
  convw_kernel<<<dim3(32, 32, 1),  256, 0, stream>>>(Wo, WoT, 1024, 1024);
  convw_kernel<<<dim3(128, 32, 1), 256, 0, stream>>>(W1, W1T, 1024, 4096);
  convw_kernel<<<dim3(32, 128, 1), 256, 0, stream>>>(W2, W2T, 4096, 1024);

  // 2. LN1
  ln_kernel<<<4096, 256, 0, stream>>>(x, ln1w, ln1b, xn);
  // 3. fused QKV projection
  gemm_bt<0><<<dim3(24, 32), 256, 0, stream>>>(xn, WqkvT, qkv, nullptr, nullptr, 4096, 3072, 1024);
  // 4. causal attention
  attn_kernel<<<16384, 256, 0, stream>>>(qkv, oc);
  // 5. output projection + bias + residual -> x1 (fp32)
  gemm_bt<1><<<dim3(8, 32), 256, 0, stream>>>(oc, WoT, x1, bo, x, 4096, 1024, 1024);
  // 6. LN2
  ln_kernel<<<4096, 256, 0, stream>>>(x1, ln2w, ln2b, xn);
  // 7. FFN1 + relu -> h (bf16)
  gemm_bt<2><<<dim3(32, 32), 256, 0, stream>>>(xn, W1T, hbuf, b1, nullptr, 4096, 4096, 1024);
  // 8. FFN2 + bias + residual -> out (fp32)
  gemm_bt<1><<<dim3(8, 32), 256, 0, stream>>>(hbuf, W2T, (float*)d_out, b2, x1, 4096, 1024, 4096);
}

// Round 2
// 346.448 us; speedup vs baseline: 4.3989x; 4.3989x over previous
//
#include <hip/hip_runtime.h>
#include <hip/hip_bf16.h>
#include <stdint.h>

#define DEV static __device__ __forceinline__

using f32x4  = __attribute__((ext_vector_type(4))) float;
using bf16x8 = __attribute__((ext_vector_type(8))) __bf16;

constexpr int SEQ = 2048;

DEV unsigned short f2bf(float f) {
  union { float f; unsigned u; } c; c.f = f;
  unsigned u = c.u;
  u += 0x7fffu + ((u >> 16) & 1u);   // RNE
  return (unsigned short)(u >> 16);
}
DEV float bf2f(unsigned short h) {
  union { unsigned u; float f; } c; c.u = ((unsigned)h) << 16;
  return c.f;
}

DEV float wred_sum(float v) {
  #pragma unroll
  for (int m = 32; m > 0; m >>= 1) v += __shfl_xor(v, m, 64);
  return v;
}

// ---------------- weight transpose + fp32->bf16 convert ----------------
__global__ __launch_bounds__(256) void convw_kernel(
    const float* __restrict__ in, unsigned short* __restrict__ out,
    int K, int Nh)
{
  const int h = blockIdx.z;
  const float* inh = in + (size_t)h * K * Nh;
  unsigned short* outh = out + (size_t)h * Nh * K;
  const int n0 = blockIdx.x * 32, k0 = blockIdx.y * 32;
  __shared__ float t[32][33];
  const int tx = threadIdx.x & 31, ty = threadIdx.x >> 5;
  #pragma unroll
  for (int r = 0; r < 32; r += 8)
    t[ty + r][tx] = inh[(size_t)(k0 + ty + r) * Nh + (n0 + tx)];
  __syncthreads();
  #pragma unroll
  for (int r = 0; r < 32; r += 8)
    outh[(size_t)(n0 + ty + r) * K + (k0 + tx)] = f2bf(t[tx][ty + r]);
}

// ---------------- LayerNorm (fp32 in) -> bf16 out ----------------
__global__ __launch_bounds__(256) void ln_kernel(
    const float* __restrict__ x, const float* __restrict__ w,
    const float* __restrict__ b, unsigned short* __restrict__ out)
{
  const int row = blockIdx.x;
  const int tid = threadIdx.x;
  const float4 v = ((const float4*)(x + (size_t)row * 1024))[tid];
  float s  = v.x + v.y + v.z + v.w;
  float s2 = v.x*v.x + v.y*v.y + v.z*v.z + v.w*v.w;
  s = wred_sum(s); s2 = wred_sum(s2);
  __shared__ float rs[4], rs2[4];
  const int wave = tid >> 6, lane = tid & 63;
  if (lane == 0) { rs[wave] = s; rs2[wave] = s2; }
  __syncthreads();
  const float S  = rs[0] + rs[1] + rs[2] + rs[3];
  const float S2 = rs2[0] + rs2[1] + rs2[2] + rs2[3];
  const float mean = S * (1.f / 1024.f);
  const float var  = S2 * (1.f / 1024.f) - mean * mean;
  const float inv  = rsqrtf(var + 1e-5f);
  const float4 wv = ((const float4*)w)[tid];
  const float4 bv = ((const float4*)b)[tid];
  ushort4 o;
  o.x = f2bf((v.x - mean) * inv * wv.x + bv.x);
  o.y = f2bf((v.y - mean) * inv * wv.y + bv.y);
  o.z = f2bf((v.z - mean) * inv * wv.z + bv.z);
  o.w = f2bf((v.w - mean) * inv * wv.w + bv.w);
  ((ushort4*)(out + (size_t)row * 1024))[tid] = o;
}

// ---------------- GEMM: C[M,N] = A[M,K] * BT[N,K]^T  (bf16 in, fp32 acc) ----
#define BM 128
#define BN 128
#define BK 32
template<int EPI>
__global__ __launch_bounds__(256) void gemm_bt(
    const unsigned short* __restrict__ A, const unsigned short* __restrict__ BT,
    void* __restrict__ Cout, const float* __restrict__ bias,
    const float* __restrict__ res, int M, int N, int K)
{
  __shared__ unsigned short sA[BM * BK];
  __shared__ unsigned short sB[BN * BK];
  const int tid = threadIdx.x;
  const int wave = tid >> 6, lane = tid & 63;
  const int wr = wave >> 1, wc = wave & 1;
  const int m0 = blockIdx.y * BM, n0 = blockIdx.x * BN;
  const int lr = lane & 15, lg = lane >> 4;

  const f32x4 zero = {0.f, 0.f, 0.f, 0.f};
  f32x4 acc[4][4];
  #pragma unroll
  for (int i = 0; i < 4; ++i)
    #pragma unroll
    for (int j = 0; j < 4; ++j) acc[i][j] = zero;

  for (int k0 = 0; k0 < K; k0 += BK) {
    #pragma unroll
    for (int r = 0; r < 2; ++r) {
      const int c = tid + 256 * r;
      const int row = c >> 2, off = (c & 3) * 8;
      const int4 va = *(const int4*)(A + (size_t)(m0 + row) * K + k0 + off);
      *(int4*)(sA + row * BK + off) = va;
      const int4 vb = *(const int4*)(BT + (size_t)(n0 + row) * K + k0 + off);
      *(int4*)(sB + row * BK + off) = vb;
    }
    __syncthreads();
    bf16x8 af[4], bfr[4];
    #pragma unroll
    for (int i = 0; i < 4; ++i) {
      af[i]  = *(const bf16x8*)(sA + (wr * 64 + i * 16 + lr) * BK + lg * 8);
      bfr[i] = *(const bf16x8*)(sB + (wc * 64 + i * 16 + lr) * BK + lg * 8);
    }
    #pragma unroll
    for (int i = 0; i < 4; ++i)
      #pragma unroll
      for (int j = 0; j < 4; ++j)
        acc[i][j] = __builtin_amdgcn_mfma_f32_16x16x32_bf16(af[i], bfr[j], acc[i][j], 0, 0, 0);
    __syncthreads();
  }
  #pragma unroll
  for (int i = 0; i < 4; ++i) {
    #pragma unroll
    for (int j = 0; j < 4; ++j) {
      #pragma unroll
      for (int r = 0; r < 4; ++r) {
        const int row = m0 + wr * 64 + i * 16 + lg * 4 + r;
        const int col = n0 + wc * 64 + j * 16 + lr;
        const float v = acc[i][j][r];
        if (EPI == 0) {
          ((unsigned short*)Cout)[(size_t)row * N + col] = f2bf(v);
        } else if (EPI == 1) {
          ((float*)Cout)[(size_t)row * N + col] = v + bias[col] + res[(size_t)row * N + col];
        } else {
          float t = v + bias[col];
          t = t > 0.f ? t : 0.f;
          ((unsigned short*)Cout)[(size_t)row * N + col] = f2bf(t);
        }
      }
    }
  }
}

// ---------------- MFMA flash attention (causal) ----------------
// qkv: [B*S][3072] bf16 (q|k|v, head-major h*64+dh), o: [B*S][1024] bf16
// block = 4 waves; wave owns 16 q-rows; KV tile = 64 keys.
constexpr int PAD = 72;   // LDS row stride (elems): 144B -> 4-bank shift/row

__global__ __launch_bounds__(256) void attn_mfma(
    const unsigned short* __restrict__ qkv, unsigned short* __restrict__ o)
{
  const int qi = blockIdx.x >> 5;          // q-block index (balances causal work)
  const int bh = blockIdx.x & 31;
  const int b = bh >> 4, h = bh & 15;
  const int q0 = qi * 64;
  const int tid = threadIdx.x;
  const int wave = tid >> 6, lane = tid & 63;
  const int lr = lane & 15, lg = lane >> 4;

  __shared__ unsigned short Ks[64 * PAD];        // Ks[j][k]
  __shared__ unsigned short Vs[64 * PAD];        // Vs[d][key]  (transposed)
  __shared__ unsigned short Ps[4][16 * PAD];     // per-wave P tile

  // Q A-fragments, loaded once: A[m=lr][k=(lg)*8+e], rows q0+wave*16+lr
  const int qrow = q0 + wave * 16 + lr;
  const size_t qbase = ((size_t)(b * SEQ + qrow)) * 3072 + h * 64;
  bf16x8 qf[2];
  qf[0] = *(const bf16x8*)(qkv + qbase + lg * 8);
  qf[1] = *(const bf16x8*)(qkv + qbase + 32 + lg * 8);

  const f32x4 zero = {0.f, 0.f, 0.f, 0.f};
  f32x4 o_acc[4];
  #pragma unroll
  for (int dn = 0; dn < 4; ++dn) o_acc[dn] = zero;
  float m_run[4] = {-1e30f, -1e30f, -1e30f, -1e30f};
  float l_run[4] = {0.f, 0.f, 0.f, 0.f};

  const int ntiles = qi + 1;
  for (int t = 0; t < ntiles; ++t) {
    const int j0 = t * 64;
    __syncthreads();
    // stage K row-major: chunk c -> row=c>>3, seg=c&7 (coalesced 128B/row-pair)
    #pragma unroll
    for (int c = tid; c < 512; c += 256) {
      const int row = c >> 3, seg = c & 7;
      const size_t base = ((size_t)(b * SEQ + j0 + row)) * 3072 + 1024 + h * 64 + seg * 8;
      *(int4*)(Ks + row * PAD + seg * 8) = *(const int4*)(qkv + base);
    }
    // stage V transposed: chunk c -> key=c&63, dseg=c>>6 (conflict-free LDS writes)
    #pragma unroll
    for (int c = tid; c < 512; c += 256) {
      const int key = c & 63, dseg = c >> 6;
      const size_t base = ((size_t)(b * SEQ + j0 + key)) * 3072 + 2048 + h * 64 + dseg * 8;
      int4 rv = *(const int4*)(qkv + base);
      const unsigned short* u = (const unsigned short*)&rv;
      #pragma unroll
      for (int e = 0; e < 8; ++e) Vs[(dseg * 8 + e) * PAD + key] = u[e];
    }
    __syncthreads();

    // ---- QK^T: S[q][j], q=rows of this wave, j=j0+n*16+(lane&15) ----
    f32x4 s[4];
    #pragma unroll
    for (int n = 0; n < 4; ++n) {
      s[n] = zero;
      const bf16x8 kf0 = *(const bf16x8*)(Ks + (n * 16 + lr) * PAD + lg * 8);
      const bf16x8 kf1 = *(const bf16x8*)(Ks + (n * 16 + lr) * PAD + 32 + lg * 8);
      s[n] = __builtin_amdgcn_mfma_f32_16x16x32_bf16(qf[0], kf0, s[n], 0, 0, 0);
      s[n] = __builtin_amdgcn_mfma_f32_16x16x32_bf16(qf[1], kf1, s[n], 0, 0, 0);
    }

    // ---- online softmax on accumulator layout: row=(lg)*4+r, col=lr ----
    const bool diag = (t == ntiles - 1);
    #pragma unroll
    for (int r = 0; r < 4; ++r) {
      const int q = q0 + wave * 16 + lg * 4 + r;
      float vmax = -1e30f;
      #pragma unroll
      for (int n = 0; n < 4; ++n) {
        float sv = s[n][r] * 0.125f;
        if (diag && (j0 + n * 16 + lr > q)) sv = -1e30f;
        s[n][r] = sv;
        vmax = fmaxf(vmax, sv);
      }
      #pragma unroll
      for (int msk = 8; msk > 0; msk >>= 1) vmax = fmaxf(vmax, __shfl_xor(vmax, msk, 64));
      const float mnew = fmaxf(m_run[r], vmax);
      const float alpha = __expf(m_run[r] - mnew);
      m_run[r] = mnew;
      float psum = 0.f;
      #pragma unroll
      for (int n = 0; n < 4; ++n) {
        const float p = __expf(s[n][r] - mnew);
        psum += p;
        Ps[wave][(lg * 4 + r) * PAD + n * 16 + lr] = f2bf(p);
      }
      #pragma unroll
      for (int msk = 8; msk > 0; msk >>= 1) psum += __shfl_xor(psum, msk, 64);
      l_run[r] = l_run[r] * alpha + psum;
      #pragma unroll
      for (int dn = 0; dn < 4; ++dn) o_acc[dn] *= alpha;
    }

    // ---- PV: O[q][d] += P[q][key] * V[key][d] ----
    bf16x8 pf[2];
    pf[0] = *(const bf16x8*)(&Ps[wave][lr * PAD + lg * 8]);
    pf[1] = *(const bf16x8*)(&Ps[wave][lr * PAD + 32 + lg * 8]);
    #pragma unroll
    for (int dn = 0; dn < 4; ++dn) {
      const bf16x8 vf0 = *(const bf16x8*)(Vs + (dn * 16 + lr) * PAD + lg * 8);
      const bf16x8 vf1 = *(const bf16x8*)(Vs + (dn * 16 + lr) * PAD + 32 + lg * 8);
      o_acc[dn] = __builtin_amdgcn_mfma_f32_16x16x32_bf16(pf[0], vf0, o_acc[dn], 0, 0, 0);
      o_acc[dn] = __builtin_amdgcn_mfma_f32_16x16x32_bf16(pf[1], vf1, o_acc[dn], 0, 0, 0);
    }
  }

  // ---- epilogue ----
  #pragma unroll
  for (int r = 0; r < 4; ++r) {
    const int q = q0 + wave * 16 + lg * 4 + r;
    const float inv = 1.f / l_run[r];
    const size_t obase = ((size_t)(b * SEQ + q)) * 1024 + h * 64;
    #pragma unroll
    for (int dn = 0; dn < 4; ++dn)
      o[obase + dn * 16 + lr] = f2bf(o_acc[dn][r] * inv);
  }
}

extern "C" void kernel_launch(void* const* d_in, const int* in_sizes, int n_in,
                              void* d_out, int out_size, void* d_ws, size_t ws_size,
                              hipStream_t stream) {
  const float* x    = (const float*)d_in[0];
  const float* Wq   = (const float*)d_in[2];
  const float* Wk   = (const float*)d_in[3];
  const float* Wv   = (const float*)d_in[4];
  const float* Wo   = (const float*)d_in[5];
  const float* bo   = (const float*)d_in[6];
  const float* W1   = (const float*)d_in[7];
  const float* b1   = (const float*)d_in[8];
  const float* W2   = (const float*)d_in[9];
  const float* b2   = (const float*)d_in[10];
  const float* ln1w = (const float*)d_in[11];
  const float* ln1b = (const float*)d_in[12];
  const float* ln2w = (const float*)d_in[13];
  const float* ln2b = (const float*)d_in[14];

  char* ws = (char*)d_ws;
  unsigned short* WqkvT = (unsigned short*)(ws);             // [3072][1024] bf16
  unsigned short* WoT   = (unsigned short*)(ws + 6291456);   // [1024][1024]
  unsigned short* W1T   = (unsigned short*)(ws + 8388608);   // [4096][1024]
  unsigned short* W2T   = (unsigned short*)(ws + 16777216);  // [1024][4096]
  unsigned short* xn    = (unsigned short*)(ws + 25165824);  // [4096][1024]
  float*          x1    = (float*)        (ws + 33554432);   // [4096][1024] fp32
  unsigned short* qkv   = (unsigned short*)(ws + 50331648);  // [4096][3072]
  unsigned short* oc    = (unsigned short*)(ws + 75497472);  // [4096][1024]
  unsigned short* hbuf  = qkv;                               // [4096][4096] aliases qkv+oc

  convw_kernel<<<dim3(2, 32, 16),  256, 0, stream>>>(Wq, WqkvT,               1024, 64);
  convw_kernel<<<dim3(2, 32, 16),  256, 0, stream>>>(Wk, WqkvT + 1024 * 1024, 1024, 64);
  convw_kernel<<<dim3(2, 32, 16),  256, 0, stream>>>(Wv, WqkvT + 2048 * 1024, 1024, 64);
  convw_kernel<<<dim3(32, 32, 1),  256, 0, stream>>>(Wo, WoT, 1024, 1024);
  convw_kernel<<<dim3(128, 32, 1), 256, 0, stream>>>(W1, W1T, 1024, 4096);
  convw_kernel<<<dim3(32, 128, 1), 256, 0, stream>>>(W2, W2T, 4096, 1024);

  ln_kernel<<<4096, 256, 0, stream>>>(x, ln1w, ln1b, xn);
  gemm_bt<0><<<dim3(24, 32), 256, 0, stream>>>(xn, WqkvT, qkv, nullptr, nullptr, 4096, 3072, 1024);
  attn_mfma<<<1024, 256, 0, stream>>>(qkv, oc);
  gemm_bt<1><<<dim3(8, 32), 256, 0, stream>>>(oc, WoT, x1, bo, x, 4096, 1024, 1024);
  ln_kernel<<<4096, 256, 0, stream>>>(x1, ln2w, ln2b, xn);
  gemm_bt<2><<<dim3(32, 32), 256, 0, stream>>>(xn, W1T, hbuf, b1, nullptr, 4096, 4096, 1024);
  gemm_bt<1><<<dim3(8, 32), 256, 0, stream>>>(hbuf, W2T, (float*)d_out, b2, x1, 4096, 1024, 4096);
}

// Round 3
// 337.741 us; speedup vs baseline: 4.5123x; 1.0258x over previous
//
#include <hip/hip_runtime.h>
#include <hip/hip_bf16.h>
#include <stdint.h>

#define DEV static __device__ __forceinline__

using f32x4  = __attribute__((ext_vector_type(4))) float;
using bf16x8 = __attribute__((ext_vector_type(8))) __bf16;

constexpr int SEQ = 2048;

DEV unsigned short f2bf(float f) {
  union { float f; unsigned u; } c; c.f = f;
  unsigned u = c.u;
  u += 0x7fffu + ((u >> 16) & 1u);   // RNE
  return (unsigned short)(u >> 16);
}
DEV float bf2f(unsigned short h) {
  union { unsigned u; float f; } c; c.u = ((unsigned)h) << 16;
  return c.f;
}

DEV float wred_sum(float v) {
  #pragma unroll
  for (int m = 32; m > 0; m >>= 1) v += __shfl_xor(v, m, 64);
  return v;
}

// async global->LDS, 16B per lane. LDS dest = wave-uniform base + lane*16.
DEV void g2l16(const unsigned short* g, unsigned short* l) {
  __builtin_amdgcn_global_load_lds(
      (const __attribute__((address_space(1))) void*)g,
      (__attribute__((address_space(3))) void*)l, 16, 0, 0);
}

// ---------------- weight transpose + fp32->bf16 convert ----------------
__global__ __launch_bounds__(256) void convw_kernel(
    const float* __restrict__ in, unsigned short* __restrict__ out,
    int K, int Nh)
{
  const int h = blockIdx.z;
  const float* inh = in + (size_t)h * K * Nh;
  unsigned short* outh = out + (size_t)h * Nh * K;
  const int n0 = blockIdx.x * 32, k0 = blockIdx.y * 32;
  __shared__ float t[32][33];
  const int tx = threadIdx.x & 31, ty = threadIdx.x >> 5;
  #pragma unroll
  for (int r = 0; r < 32; r += 8)
    t[ty + r][tx] = inh[(size_t)(k0 + ty + r) * Nh + (n0 + tx)];
  __syncthreads();
  #pragma unroll
  for (int r = 0; r < 32; r += 8)
    outh[(size_t)(n0 + ty + r) * K + (k0 + tx)] = f2bf(t[tx][ty + r]);
}

// ---------------- LayerNorm (fp32 in) -> bf16 out ----------------
__global__ __launch_bounds__(256) void ln_kernel(
    const float* __restrict__ x, const float* __restrict__ w,
    const float* __restrict__ b, unsigned short* __restrict__ out)
{
  const int row = blockIdx.x;
  const int tid = threadIdx.x;
  const float4 v = ((const float4*)(x + (size_t)row * 1024))[tid];
  float s  = v.x + v.y + v.z + v.w;
  float s2 = v.x*v.x + v.y*v.y + v.z*v.z + v.w*v.w;
  s = wred_sum(s); s2 = wred_sum(s2);
  __shared__ float rs[4], rs2[4];
  const int wave = tid >> 6, lane = tid & 63;
  if (lane == 0) { rs[wave] = s; rs2[wave] = s2; }
  __syncthreads();
  const float S  = rs[0] + rs[1] + rs[2] + rs[3];
  const float S2 = rs2[0] + rs2[1] + rs2[2] + rs2[3];
  const float mean = S * (1.f / 1024.f);
  const float var  = S2 * (1.f / 1024.f) - mean * mean;
  const float inv  = rsqrtf(var + 1e-5f);
  const float4 wv = ((const float4*)w)[tid];
  const float4 bv = ((const float4*)b)[tid];
  ushort4 o;
  o.x = f2bf((v.x - mean) * inv * wv.x + bv.x);
  o.y = f2bf((v.y - mean) * inv * wv.y + bv.y);
  o.z = f2bf((v.z - mean) * inv * wv.z + bv.z);
  o.w = f2bf((v.w - mean) * inv * wv.w + bv.w);
  ((ushort4*)(out + (size_t)row * 1024))[tid] = o;
}

// ---------------- GEMM: C[M,N] = A[M,K] * BT[N,K]^T  (bf16 in, fp32 acc) ----
// staging via global_load_lds width=16 (m97 structure):
//   thread c fills LDS elems [8c,8c+8) == row(c>>2)*BK + (c&3)*8  (linear)
#define BM 128
#define BN 128
#define BK 32
template<int EPI>
__global__ __launch_bounds__(256) void gemm_bt(
    const unsigned short* __restrict__ A, const unsigned short* __restrict__ BT,
    void* __restrict__ Cout, const float* __restrict__ bias,
    const float* __restrict__ res, int M, int N, int K)
{
  __shared__ unsigned short sA[BM * BK];
  __shared__ unsigned short sB[BN * BK];
  const int tid = threadIdx.x;
  const int wave = tid >> 6, lane = tid & 63;
  const int wr = wave >> 1, wc = wave & 1;
  const int m0 = blockIdx.y * BM, n0 = blockIdx.x * BN;
  const int lr = lane & 15, lg = lane >> 4;
  const int wb = tid & 192;                 // wave*64 (uniform in wave)

  const f32x4 zero = {0.f, 0.f, 0.f, 0.f};
  f32x4 acc[4][4];
  #pragma unroll
  for (int i = 0; i < 4; ++i)
    #pragma unroll
    for (int j = 0; j < 4; ++j) acc[i][j] = zero;

  for (int k0 = 0; k0 < K; k0 += BK) {
    #pragma unroll
    for (int r = 0; r < 2; ++r) {
      const int c = tid + 256 * r;
      const int row = c >> 2, off = (c & 3) * 8;
      g2l16(A  + (size_t)(m0 + row) * K + k0 + off, sA + (size_t)(r * 256 + wb) * 8);
      g2l16(BT + (size_t)(n0 + row) * K + k0 + off, sB + (size_t)(r * 256 + wb) * 8);
    }
    __syncthreads();
    bf16x8 af[4], bfr[4];
    #pragma unroll
    for (int i = 0; i < 4; ++i) {
      af[i]  = *(const bf16x8*)(sA + (wr * 64 + i * 16 + lr) * BK + lg * 8);
      bfr[i] = *(const bf16x8*)(sB + (wc * 64 + i * 16 + lr) * BK + lg * 8);
    }
    #pragma unroll
    for (int i = 0; i < 4; ++i)
      #pragma unroll
      for (int j = 0; j < 4; ++j)
        acc[i][j] = __builtin_amdgcn_mfma_f32_16x16x32_bf16(af[i], bfr[j], acc[i][j], 0, 0, 0);
    __syncthreads();
  }
  #pragma unroll
  for (int i = 0; i < 4; ++i) {
    #pragma unroll
    for (int j = 0; j < 4; ++j) {
      #pragma unroll
      for (int r = 0; r < 4; ++r) {
        const int row = m0 + wr * 64 + i * 16 + lg * 4 + r;
        const int col = n0 + wc * 64 + j * 16 + lr;
        const float v = acc[i][j][r];
        if (EPI == 0) {
          ((unsigned short*)Cout)[(size_t)row * N + col] = f2bf(v);
        } else if (EPI == 1) {
          ((float*)Cout)[(size_t)row * N + col] = v + bias[col] + res[(size_t)row * N + col];
        } else {
          float t = v + bias[col];
          t = t > 0.f ? t : 0.f;
          ((unsigned short*)Cout)[(size_t)row * N + col] = f2bf(t);
        }
      }
    }
  }
}

// ---------------- MFMA flash attention (causal) ----------------
constexpr int PAD = 72;   // LDS row stride (elems)

__global__ __launch_bounds__(256) void attn_mfma(
    const unsigned short* __restrict__ qkv, unsigned short* __restrict__ o)
{
  // heavy-first: qi descending with blockIdx so long blocks start first
  const int qi = 31 - (blockIdx.x >> 5);
  const int bh = blockIdx.x & 31;
  const int b = bh >> 4, h = bh & 15;
  const int q0 = qi * 64;
  const int tid = threadIdx.x;
  const int wave = tid >> 6, lane = tid & 63;
  const int lr = lane & 15, lg = lane >> 4;

  __shared__ unsigned short Ks[64 * PAD];        // Ks[j][k]
  __shared__ unsigned short Vs[64 * PAD];        // Vs[d][key]  (transposed)
  __shared__ unsigned short Ps[4][16 * PAD];     // per-wave P tile

  const int qrow = q0 + wave * 16 + lr;
  const size_t qbase = ((size_t)(b * SEQ + qrow)) * 3072 + h * 64;
  bf16x8 qf[2];
  qf[0] = *(const bf16x8*)(qkv + qbase + lg * 8);
  qf[1] = *(const bf16x8*)(qkv + qbase + 32 + lg * 8);

  const f32x4 zero = {0.f, 0.f, 0.f, 0.f};
  f32x4 o_acc[4];
  #pragma unroll
  for (int dn = 0; dn < 4; ++dn) o_acc[dn] = zero;
  float m_run[4] = {-1e30f, -1e30f, -1e30f, -1e30f};
  float l_run[4] = {0.f, 0.f, 0.f, 0.f};

  const int ntiles = qi + 1;
  for (int t = 0; t < ntiles; ++t) {
    const int j0 = t * 64;
    __syncthreads();
    #pragma unroll
    for (int c = tid; c < 512; c += 256) {
      const int row = c >> 3, seg = c & 7;
      const size_t base = ((size_t)(b * SEQ + j0 + row)) * 3072 + 1024 + h * 64 + seg * 8;
      *(int4*)(Ks + row * PAD + seg * 8) = *(const int4*)(qkv + base);
    }
    #pragma unroll
    for (int c = tid; c < 512; c += 256) {
      const int key = c & 63, dseg = c >> 6;
      const size_t base = ((size_t)(b * SEQ + j0 + key)) * 3072 + 2048 + h * 64 + dseg * 8;
      int4 rv = *(const int4*)(qkv + base);
      const unsigned short* u = (const unsigned short*)&rv;
      #pragma unroll
      for (int e = 0; e < 8; ++e) Vs[(dseg * 8 + e) * PAD + key] = u[e];
    }
    __syncthreads();

    // QK^T
    f32x4 s[4];
    #pragma unroll
    for (int n = 0; n < 4; ++n) {
      s[n] = zero;
      const bf16x8 kf0 = *(const bf16x8*)(Ks + (n * 16 + lr) * PAD + lg * 8);
      const bf16x8 kf1 = *(const bf16x8*)(Ks + (n * 16 + lr) * PAD + 32 + lg * 8);
      s[n] = __builtin_amdgcn_mfma_f32_16x16x32_bf16(qf[0], kf0, s[n], 0, 0, 0);
      s[n] = __builtin_amdgcn_mfma_f32_16x16x32_bf16(qf[1], kf1, s[n], 0, 0, 0);
    }

    // online softmax (acc layout: row=lg*4+r, col=lr)
    const bool diag = (t == ntiles - 1);
    #pragma unroll
    for (int r = 0; r < 4; ++r) {
      const int q = q0 + wave * 16 + lg * 4 + r;
      float vmax = -1e30f;
      #pragma unroll
      for (int n = 0; n < 4; ++n) {
        float sv = s[n][r] * 0.125f;
        if (diag && (j0 + n * 16 + lr > q)) sv = -1e30f;
        s[n][r] = sv;
        vmax = fmaxf(vmax, sv);
      }
      #pragma unroll
      for (int msk = 8; msk > 0; msk >>= 1) vmax = fmaxf(vmax, __shfl_xor(vmax, msk, 64));
      const float mnew = fmaxf(m_run[r], vmax);
      const float alpha = __expf(m_run[r] - mnew);
      m_run[r] = mnew;
      float psum = 0.f;
      #pragma unroll
      for (int n = 0; n < 4; ++n) {
        const float p = __expf(s[n][r] - mnew);
        psum += p;
        Ps[wave][(lg * 4 + r) * PAD + n * 16 + lr] = f2bf(p);
      }
      #pragma unroll
      for (int msk = 8; msk > 0; msk >>= 1) psum += __shfl_xor(psum, msk, 64);
      l_run[r] = l_run[r] * alpha + psum;
      #pragma unroll
      for (int dn = 0; dn < 4; ++dn) o_acc[dn] *= alpha;
    }

    // PV
    bf16x8 pf[2];
    pf[0] = *(const bf16x8*)(&Ps[wave][lr * PAD + lg * 8]);
    pf[1] = *(const bf16x8*)(&Ps[wave][lr * PAD + 32 + lg * 8]);
    #pragma unroll
    for (int dn = 0; dn < 4; ++dn) {
      const bf16x8 vf0 = *(const bf16x8*)(Vs + (dn * 16 + lr) * PAD + lg * 8);
      const bf16x8 vf1 = *(const bf16x8*)(Vs + (dn * 16 + lr) * PAD + 32 + lg * 8);
      o_acc[dn] = __builtin_amdgcn_mfma_f32_16x16x32_bf16(pf[0], vf0, o_acc[dn], 0, 0, 0);
      o_acc[dn] = __builtin_amdgcn_mfma_f32_16x16x32_bf16(pf[1], vf1, o_acc[dn], 0, 0, 0);
    }
  }

  #pragma unroll
  for (int r = 0; r < 4; ++r) {
    const int q = q0 + wave * 16 + lg * 4 + r;
    const float inv = 1.f / l_run[r];
    const size_t obase = ((size_t)(b * SEQ + q)) * 1024 + h * 64;
    #pragma unroll
    for (int dn = 0; dn < 4; ++dn)
      o[obase + dn * 16 + lr] = f2bf(o_acc[dn][r] * inv);
  }
}

extern "C" void kernel_launch(void* const* d_in, const int* in_sizes, int n_in,
                              void* d_out, int out_size, void* d_ws, size_t ws_size,
                              hipStream_t stream) {
  const float* x    = (const float*)d_in[0];
  const float* Wq   = (const float*)d_in[2];
  const float* Wk   = (const float*)d_in[3];
  const float* Wv   = (const float*)d_in[4];
  const float* Wo   = (const float*)d_in[5];
  const float* bo   = (const float*)d_in[6];
  const float* W1   = (const float*)d_in[7];
  const float* b1   = (const float*)d_in[8];
  const float* W2   = (const float*)d_in[9];
  const float* b2   = (const float*)d_in[10];
  const float* ln1w = (const float*)d_in[11];
  const float* ln1b = (const float*)d_in[12];
  const float* ln2w = (const float*)d_in[13];
  const float* ln2b = (const float*)d_in[14];

  char* ws = (char*)d_ws;
  unsigned short* WqkvT = (unsigned short*)(ws);             // [3072][1024] bf16
  unsigned short* WoT   = (unsigned short*)(ws + 6291456);   // [1024][1024]
  unsigned short* W1T   = (unsigned short*)(ws + 8388608);   // [4096][1024]
  unsigned short* W2T   = (unsigned short*)(ws + 16777216);  // [1024][4096]
  unsigned short* xn    = (unsigned short*)(ws + 25165824);  // [4096][1024]
  float*          x1    = (float*)        (ws + 33554432);   // [4096][1024] fp32
  unsigned short* qkv   = (unsigned short*)(ws + 50331648);  // [4096][3072]
  unsigned short* oc    = (unsigned short*)(ws + 75497472);  // [4096][1024]
  unsigned short* hbuf  = qkv;                               // aliases qkv+oc

  convw_kernel<<<dim3(2, 32, 16),  256, 0, stream>>>(Wq, WqkvT,               1024, 64);
  convw_kernel<<<dim3(2, 32, 16),  256, 0, stream>>>(Wk, WqkvT + 1024 * 1024, 1024, 64);
  convw_kernel<<<dim3(2, 32, 16),  256, 0, stream>>>(Wv, WqkvT + 2048 * 1024, 1024, 64);
  convw_kernel<<<dim3(32, 32, 1),  256, 0, stream>>>(Wo, WoT, 1024, 1024);
  convw_kernel<<<dim3(128, 32, 1), 256, 0, stream>>>(W1, W1T, 1024, 4096);
  convw_kernel<<<dim3(32, 128, 1), 256, 0, stream>>>(W2, W2T, 4096, 1024);

  ln_kernel<<<4096, 256, 0, stream>>>(x, ln1w, ln1b, xn);
  gemm_bt<0><<<dim3(24, 32), 256, 0, stream>>>(xn, WqkvT, qkv, nullptr, nullptr, 4096, 3072, 1024);
  attn_mfma<<<1024, 256, 0, stream>>>(qkv, oc);
  gemm_bt<1><<<dim3(8, 32), 256, 0, stream>>>(oc, WoT, x1, bo, x, 4096, 1024, 1024);
  ln_kernel<<<4096, 256, 0, stream>>>(x1, ln2w, ln2b, xn);
  gemm_bt<2><<<dim3(32, 32), 256, 0, stream>>>(xn, W1T, hbuf, b1, nullptr, 4096, 4096, 1024);
  gemm_bt<1><<<dim3(8, 32), 256, 0, stream>>>(hbuf, W2T, (float*)d_out, b2, x1, 4096, 1024, 4096);
}

// Round 4
// 292.697 us; speedup vs baseline: 5.2067x; 1.1539x over previous
//
#include <hip/hip_runtime.h>
#include <hip/hip_bf16.h>
#include <stdint.h>

#define DEV static __device__ __forceinline__

using f32x4  = __attribute__((ext_vector_type(4))) float;
using bf16x8 = __attribute__((ext_vector_type(8))) __bf16;

constexpr int SEQ = 2048;

DEV unsigned short f2bf(float f) {
  union { float f; unsigned u; } c; c.f = f;
  unsigned u = c.u;
  u += 0x7fffu + ((u >> 16) & 1u);   // RNE
  return (unsigned short)(u >> 16);
}

DEV float wred_sum(float v) {
  #pragma unroll
  for (int m = 32; m > 0; m >>= 1) v += __shfl_xor(v, m, 64);
  return v;
}

// async global->LDS, 16B per lane. LDS dest = wave-uniform base + lane*16.
DEV void g2l16(const unsigned short* g, unsigned short* l) {
  __builtin_amdgcn_global_load_lds(
      (const __attribute__((address_space(1))) void*)g,
      (__attribute__((address_space(3))) void*)l, 16, 0, 0);
}

// ---------------- weight transpose + fp32->bf16 convert ----------------
__global__ __launch_bounds__(256) void convw_kernel(
    const float* __restrict__ in, unsigned short* __restrict__ out,
    int K, int Nh)
{
  const int h = blockIdx.z;
  const float* inh = in + (size_t)h * K * Nh;
  unsigned short* outh = out + (size_t)h * Nh * K;
  const int n0 = blockIdx.x * 32, k0 = blockIdx.y * 32;
  __shared__ float t[32][33];
  const int tx = threadIdx.x & 31, ty = threadIdx.x >> 5;
  #pragma unroll
  for (int r = 0; r < 32; r += 8)
    t[ty + r][tx] = inh[(size_t)(k0 + ty + r) * Nh + (n0 + tx)];
  __syncthreads();
  #pragma unroll
  for (int r = 0; r < 32; r += 8)
    outh[(size_t)(n0 + ty + r) * K + (k0 + tx)] = f2bf(t[tx][ty + r]);
}

// ---------------- LayerNorm (fp32 in) -> bf16 out ----------------
__global__ __launch_bounds__(256) void ln_kernel(
    const float* __restrict__ x, const float* __restrict__ w,
    const float* __restrict__ b, unsigned short* __restrict__ out)
{
  const int row = blockIdx.x;
  const int tid = threadIdx.x;
  const float4 v = ((const float4*)(x + (size_t)row * 1024))[tid];
  float s  = v.x + v.y + v.z + v.w;
  float s2 = v.x*v.x + v.y*v.y + v.z*v.z + v.w*v.w;
  s = wred_sum(s); s2 = wred_sum(s2);
  __shared__ float rs[4], rs2[4];
  const int wave = tid >> 6, lane = tid & 63;
  if (lane == 0) { rs[wave] = s; rs2[wave] = s2; }
  __syncthreads();
  const float S  = rs[0] + rs[1] + rs[2] + rs[3];
  const float S2 = rs2[0] + rs2[1] + rs2[2] + rs2[3];
  const float mean = S * (1.f / 1024.f);
  const float var  = S2 * (1.f / 1024.f) - mean * mean;
  const float inv  = rsqrtf(var + 1e-5f);
  const float4 wv = ((const float4*)w)[tid];
  const float4 bv = ((const float4*)b)[tid];
  ushort4 o;
  o.x = f2bf((v.x - mean) * inv * wv.x + bv.x);
  o.y = f2bf((v.y - mean) * inv * wv.y + bv.y);
  o.z = f2bf((v.z - mean) * inv * wv.z + bv.z);
  o.w = f2bf((v.w - mean) * inv * wv.w + bv.w);
  ((ushort4*)(out + (size_t)row * 1024))[tid] = o;
}

// ---------------- GEMM: C[M,N] = A[M,K] * BT[N,K]^T  (bf16 in, fp32 acc) ----
// 2-phase pipeline: issue next tile's global_load_lds BEFORE this tile's MFMAs;
// __syncthreads' implicit vmcnt(0) drain lands after compute (T3 min recipe).
#define BM 128
#define BN 128
#define BK 32
template<int EPI>
__global__ __launch_bounds__(256) void gemm_bt(
    const unsigned short* __restrict__ A, const unsigned short* __restrict__ BT,
    void* __restrict__ Cout, const float* __restrict__ bias,
    const float* __restrict__ res, int M, int N, int K)
{
  __shared__ unsigned short sA[2][BM * BK];
  __shared__ unsigned short sB[2][BN * BK];
  const int tid = threadIdx.x;
  const int wave = tid >> 6, lane = tid & 63;
  const int wr = wave >> 1, wc = wave & 1;
  const int m0 = blockIdx.y * BM, n0 = blockIdx.x * BN;
  const int lr = lane & 15, lg = lane >> 4;
  const int wb = tid & 192;                 // wave*64 (uniform in wave)

  const f32x4 zero = {0.f, 0.f, 0.f, 0.f};
  f32x4 acc[4][4];
  #pragma unroll
  for (int i = 0; i < 4; ++i)
    #pragma unroll
    for (int j = 0; j < 4; ++j) acc[i][j] = zero;

  auto STAGE = [&](int buf, int k0) {
    #pragma unroll
    for (int r = 0; r < 2; ++r) {
      const int c = tid + 256 * r;
      const int row = c >> 2, off = (c & 3) * 8;
      g2l16(A  + (size_t)(m0 + row) * K + k0 + off, sA[buf] + (size_t)(r * 256 + wb) * 8);
      g2l16(BT + (size_t)(n0 + row) * K + k0 + off, sB[buf] + (size_t)(r * 256 + wb) * 8);
    }
  };

  const int nt = K / BK;
  STAGE(0, 0);
  __syncthreads();
  for (int t = 0; t < nt; ++t) {
    const int buf = t & 1;
    if (t + 1 < nt) STAGE(buf ^ 1, (t + 1) * BK);
    bf16x8 af[4], bfr[4];
    #pragma unroll
    for (int i = 0; i < 4; ++i) {
      af[i]  = *(const bf16x8*)(sA[buf] + (wr * 64 + i * 16 + lr) * BK + lg * 8);
      bfr[i] = *(const bf16x8*)(sB[buf] + (wc * 64 + i * 16 + lr) * BK + lg * 8);
    }
    #pragma unroll
    for (int i = 0; i < 4; ++i)
      #pragma unroll
      for (int j = 0; j < 4; ++j)
        acc[i][j] = __builtin_amdgcn_mfma_f32_16x16x32_bf16(af[i], bfr[j], acc[i][j], 0, 0, 0);
    __syncthreads();
  }
  #pragma unroll
  for (int i = 0; i < 4; ++i) {
    #pragma unroll
    for (int j = 0; j < 4; ++j) {
      #pragma unroll
      for (int r = 0; r < 4; ++r) {
        const int row = m0 + wr * 64 + i * 16 + lg * 4 + r;
        const int col = n0 + wc * 64 + j * 16 + lr;
        const float v = acc[i][j][r];
        if (EPI == 0) {
          ((unsigned short*)Cout)[(size_t)row * N + col] = f2bf(v);
        } else if (EPI == 1) {
          ((float*)Cout)[(size_t)row * N + col] = v + bias[col] + res[(size_t)row * N + col];
        } else {
          float t2 = v + bias[col];
          t2 = t2 > 0.f ? t2 : 0.f;
          ((unsigned short*)Cout)[(size_t)row * N + col] = f2bf(t2);
        }
      }
    }
  }
}

// ---------------- MFMA flash attention (causal, swapped QK^T) ----------------
// qkv: [B*S][3072] bf16 (q|k|v head-major), o: [B*S][1024] bf16.
// Block = 4 waves; wave owns 16 q-rows; KV tile 64 keys.
// Work balance: block p handles q-blocks {p, 31-p} -> exactly 33 tiles each.
constexpr int PAD = 72;

__global__ __launch_bounds__(256) void attn_mfma(
    const unsigned short* __restrict__ qkv, unsigned short* __restrict__ o)
{
  const int p  = blockIdx.x >> 5;          // 0..15
  const int bh = blockIdx.x & 31;
  const int b = bh >> 4, h = bh & 15;
  const int tid = threadIdx.x;
  const int wave = tid >> 6, lane = tid & 63;
  const int lr = lane & 15, lg = lane >> 4;
  const float SC = 0.125f * 1.44269504089f;   // scale * log2(e); use exp2

  __shared__ unsigned short Ks[64 * PAD];      // Ks[key][d]
  __shared__ unsigned short Vs[64 * PAD];      // Vs[d][key] (transposed)
  __shared__ unsigned short Ps[4][16 * PAD];   // per-wave P tile [q][key]

  #pragma unroll 1
  for (int ph = 0; ph < 2; ++ph) {
    const int qi = ph ? (31 - p) : p;
    const int q0 = qi * 64;

    // Q B-fragments: B[n=lr][k=lg*8+e], rows q0+wave*16+lr
    const size_t qbase = ((size_t)(b * SEQ + q0 + wave * 16 + lr)) * 3072 + h * 64;
    bf16x8 qb[2];
    qb[0] = *(const bf16x8*)(qkv + qbase + lg * 8);
    qb[1] = *(const bf16x8*)(qkv + qbase + 32 + lg * 8);

    const f32x4 zero = {0.f, 0.f, 0.f, 0.f};
    f32x4 o_acc[4];
    #pragma unroll
    for (int dn = 0; dn < 4; ++dn) o_acc[dn] = zero;
    float m_run = -1e30f, l_run = 0.f;       // per-lane: q-row = lr

    const int ntiles = qi + 1;
    for (int t = 0; t < ntiles; ++t) {
      const int j0 = t * 64;
      __syncthreads();
      #pragma unroll
      for (int c = tid; c < 512; c += 256) {
        const int row = c >> 3, seg = c & 7;
        const size_t base = ((size_t)(b * SEQ + j0 + row)) * 3072 + 1024 + h * 64 + seg * 8;
        *(int4*)(Ks + row * PAD + seg * 8) = *(const int4*)(qkv + base);
      }
      #pragma unroll
      for (int c = tid; c < 512; c += 256) {
        const int key = c & 63, dseg = c >> 6;
        const size_t base = ((size_t)(b * SEQ + j0 + key)) * 3072 + 2048 + h * 64 + dseg * 8;
        int4 rv = *(const int4*)(qkv + base);
        const unsigned short* u = (const unsigned short*)&rv;
        #pragma unroll
        for (int e = 0; e < 8; ++e) Vs[(dseg * 8 + e) * PAD + key] = u[e];
      }
      __syncthreads();

      // ---- QK^T swapped: D[key'=lg*4+r][q'=lr] = mfma(K, Q) ----
      f32x4 s[4];
      #pragma unroll
      for (int n = 0; n < 4; ++n) {
        const bf16x8 kf0 = *(const bf16x8*)(Ks + (n * 16 + lr) * PAD + lg * 8);
        const bf16x8 kf1 = *(const bf16x8*)(Ks + (n * 16 + lr) * PAD + 32 + lg * 8);
        s[n] = __builtin_amdgcn_mfma_f32_16x16x32_bf16(kf0, qb[0], zero, 0, 0, 0);
        s[n] = __builtin_amdgcn_mfma_f32_16x16x32_bf16(kf1, qb[1], s[n], 0, 0, 0);
      }

      // ---- in-lane online softmax: lane owns q-row lr, 16 keys n*16+lg*4+r ----
      const bool diag = (t == ntiles - 1);
      const int q = q0 + wave * 16 + lr;
      const int kbase = j0 + lg * 4;
      float zm = -3e38f;
      #pragma unroll
      for (int n = 0; n < 4; ++n)
        #pragma unroll
        for (int r = 0; r < 4; ++r) {
          float z = s[n][r] * SC;
          if (diag && (kbase + n * 16 + r > q)) z = -3e38f;
          s[n][r] = z;
          zm = fmaxf(zm, z);
        }
      zm = fmaxf(zm, __shfl_xor(zm, 16, 64));
      zm = fmaxf(zm, __shfl_xor(zm, 32, 64));
      const float mnew = fmaxf(m_run, zm);
      const float alpha = exp2f(m_run - mnew);
      m_run = mnew;
      float psum = 0.f;
      #pragma unroll
      for (int n = 0; n < 4; ++n) {
        ushort4 w;
        float p0 = exp2f(s[n][0] - mnew); psum += p0; w.x = f2bf(p0);
        float p1 = exp2f(s[n][1] - mnew); psum += p1; w.y = f2bf(p1);
        float p2 = exp2f(s[n][2] - mnew); psum += p2; w.z = f2bf(p2);
        float p3 = exp2f(s[n][3] - mnew); psum += p3; w.w = f2bf(p3);
        *(ushort4*)(&Ps[wave][lr * PAD + n * 16 + lg * 4]) = w;
      }
      psum += __shfl_xor(psum, 16, 64);
      psum += __shfl_xor(psum, 32, 64);
      l_run = l_run * alpha + psum;

      // rescale o_acc rows (row q' = lg*4+r): alpha held by lane lg*4+r
      float a4[4];
      #pragma unroll
      for (int r = 0; r < 4; ++r) a4[r] = __shfl(alpha, lg * 4 + r, 64);
      #pragma unroll
      for (int dn = 0; dn < 4; ++dn)
        #pragma unroll
        for (int r = 0; r < 4; ++r) o_acc[dn][r] *= a4[r];

      // ---- PV: D[q'=lg*4+r][d'=lr] += P * V ----
      bf16x8 pa[2];
      pa[0] = *(const bf16x8*)(&Ps[wave][lr * PAD + lg * 8]);
      pa[1] = *(const bf16x8*)(&Ps[wave][lr * PAD + 32 + lg * 8]);
      #pragma unroll
      for (int dn = 0; dn < 4; ++dn) {
        const bf16x8 vf0 = *(const bf16x8*)(Vs + (dn * 16 + lr) * PAD + lg * 8);
        const bf16x8 vf1 = *(const bf16x8*)(Vs + (dn * 16 + lr) * PAD + 32 + lg * 8);
        o_acc[dn] = __builtin_amdgcn_mfma_f32_16x16x32_bf16(pa[0], vf0, o_acc[dn], 0, 0, 0);
        o_acc[dn] = __builtin_amdgcn_mfma_f32_16x16x32_bf16(pa[1], vf1, o_acc[dn], 0, 0, 0);
      }
    }

    // ---- epilogue: row q'=lg*4+r, 1/l held by lane lg*4+r ----
    float linv[4];
    #pragma unroll
    for (int r = 0; r < 4; ++r) linv[r] = 1.f / __shfl(l_run, lg * 4 + r, 64);
    #pragma unroll
    for (int r = 0; r < 4; ++r) {
      const int qq = q0 + wave * 16 + lg * 4 + r;
      const size_t obase = ((size_t)(b * SEQ + qq)) * 1024 + h * 64;
      #pragma unroll
      for (int dn = 0; dn < 4; ++dn)
        o[obase + dn * 16 + lr] = f2bf(o_acc[dn][r] * linv[r]);
    }
  }
}

extern "C" void kernel_launch(void* const* d_in, const int* in_sizes, int n_in,
                              void* d_out, int out_size, void* d_ws, size_t ws_size,
                              hipStream_t stream) {
  const float* x    = (const float*)d_in[0];
  const float* Wq   = (const float*)d_in[2];
  const float* Wk   = (const float*)d_in[3];
  const float* Wv   = (const float*)d_in[4];
  const float* Wo   = (const float*)d_in[5];
  const float* bo   = (const float*)d_in[6];
  const float* W1   = (const float*)d_in[7];
  const float* b1   = (const float*)d_in[8];
  const float* W2   = (const float*)d_in[9];
  const float* b2   = (const float*)d_in[10];
  const float* ln1w = (const float*)d_in[11];
  const float* ln1b = (const float*)d_in[12];
  const float* ln2w = (const float*)d_in[13];
  const float* ln2b = (const float*)d_in[14];

  char* ws = (char*)d_ws;
  unsigned short* WqkvT = (unsigned short*)(ws);             // [3072][1024] bf16
  unsigned short* WoT   = (unsigned short*)(ws + 6291456);   // [1024][1024]
  unsigned short* W1T   = (unsigned short*)(ws + 8388608);   // [4096][1024]
  unsigned short* W2T   = (unsigned short*)(ws + 16777216);  // [1024][4096]
  unsigned short* xn    = (unsigned short*)(ws + 25165824);  // [4096][1024]
  float*          x1    = (float*)        (ws + 33554432);   // [4096][1024] fp32
  unsigned short* qkv   = (unsigned short*)(ws + 50331648);  // [4096][3072]
  unsigned short* oc    = (unsigned short*)(ws + 75497472);  // [4096][1024]
  unsigned short* hbuf  = qkv;                               // aliases qkv+oc

  convw_kernel<<<dim3(2, 32, 16),  256, 0, stream>>>(Wq, WqkvT,               1024, 64);
  convw_kernel<<<dim3(2, 32, 16),  256, 0, stream>>>(Wk, WqkvT + 1024 * 1024, 1024, 64);
  convw_kernel<<<dim3(2, 32, 16),  256, 0, stream>>>(Wv, WqkvT + 2048 * 1024, 1024, 64);
  convw_kernel<<<dim3(32, 32, 1),  256, 0, stream>>>(Wo, WoT, 1024, 1024);
  convw_kernel<<<dim3(128, 32, 1), 256, 0, stream>>>(W1, W1T, 1024, 4096);
  convw_kernel<<<dim3(32, 128, 1), 256, 0, stream>>>(W2, W2T, 4096, 1024);

  ln_kernel<<<4096, 256, 0, stream>>>(x, ln1w, ln1b, xn);
  gemm_bt<0><<<dim3(24, 32), 256, 0, stream>>>(xn, WqkvT, qkv, nullptr, nullptr, 4096, 3072, 1024);
  attn_mfma<<<512, 256, 0, stream>>>(qkv, oc);
  gemm_bt<1><<<dim3(8, 32), 256, 0, stream>>>(oc, WoT, x1, bo, x, 4096, 1024, 1024);
  ln_kernel<<<4096, 256, 0, stream>>>(x1, ln2w, ln2b, xn);
  gemm_bt<2><<<dim3(32, 32), 256, 0, stream>>>(xn, W1T, hbuf, b1, nullptr, 4096, 4096, 1024);
  gemm_bt<1><<<dim3(8, 32), 256, 0, stream>>>(hbuf, W2T, (float*)d_out, b2, x1, 4096, 1024, 4096);
}